// Round 11
// baseline (180.299 us; speedup 1.0000x reference)
//
#include <hip/hip_runtime.h>
#include <hip/hip_bf16.h>

typedef short bf16x8 __attribute__((ext_vector_type(8)));
typedef float f32x4 __attribute__((ext_vector_type(4)));

#define MFMA16(a, b, c) __builtin_amdgcn_mfma_f32_16x16x32_bf16(a, b, c, 0, 0, 0)

static constexpr int SEQ = 1024;
static constexpr int DIM = 1024;
static constexpr int NH = 16;
static constexpr int HD = 64;

#if __has_builtin(__builtin_amdgcn_rcpf)
#define FAST_RCP(x) __builtin_amdgcn_rcpf(x)
#else
#define FAST_RCP(x) (1.0f / (x))
#endif

#if __has_builtin(__builtin_amdgcn_exp2f)
#define EXP2F(x) __builtin_amdgcn_exp2f(x)
#else
#define EXP2F(x) exp2f(x)
#endif

__device__ __forceinline__ int swz(int r) { return r ^ (r >> 3); } // row-XOR bank swizzle

// async global->LDS, 16B per lane. lds ptr must be wave-uniform (HW adds lane*16).
__device__ __forceinline__ void gload16(const __hip_bfloat16* g, __hip_bfloat16* l)
{
    typedef const __attribute__((address_space(1))) unsigned GU;
    typedef __attribute__((address_space(3))) unsigned LU;
    __builtin_amdgcn_global_load_lds((GU*)g, (LU*)l, 16, 0, 0);
}

__device__ __forceinline__ unsigned pack2bf(float a, float b)
{
    union { __hip_bfloat16 h; unsigned short u; } ca, cb;
    ca.h = __float2bfloat16(a); cb.h = __float2bfloat16(b);
    return (unsigned)ca.u | ((unsigned)cb.u << 16);
}

// convert 8 fp32 (two float4) -> bf16x8, same rounding as the old cvt_all
__device__ __forceinline__ bf16x8 cvt8(const float4 a, const float4 b)
{
    union { __hip_bfloat16 h[8]; bf16x8 v; } u;
    u.h[0] = __float2bfloat16(a.x); u.h[1] = __float2bfloat16(a.y);
    u.h[2] = __float2bfloat16(a.z); u.h[3] = __float2bfloat16(a.w);
    u.h[4] = __float2bfloat16(b.x); u.h[5] = __float2bfloat16(b.y);
    u.h[6] = __float2bfloat16(b.z); u.h[7] = __float2bfloat16(b.w);
    return u.v;
}

// ---------------------------------------------------------------------------
// FUSED QKV GEMM: reads x and Wq/Wk/Wv in fp32, converts to bf16 in-register
// during staging (cvt_all kernel eliminated -> one fewer launch + gap).
// 64x128 tile, BK=64, both-sides XOR swizzle (read side identical to the
// R6-verified layout), single-barrier ping-pong with T14 ordering:
// loads(t+1) issue BEFORE compute(t), ds_writes land after. 768 blk = 3/CU.
// ---------------------------------------------------------------------------
__global__ __launch_bounds__(256) void gemm_qkv(
    const float* __restrict__ X,
    const float* __restrict__ W0, const float* __restrict__ W1,
    const float* __restrict__ W2,
    const float* __restrict__ b0, const float* __restrict__ b1,
    const float* __restrict__ b2,
    __hip_bfloat16* __restrict__ Y0, __hip_bfloat16* __restrict__ Y1,
    __hip_bfloat16* __restrict__ Y2,
    int M, int N, int K)
{
    __shared__ __align__(16) __hip_bfloat16 As[2][64 * 64];    // 16 KB
    __shared__ __align__(16) __hip_bfloat16 Ws[2][128 * 64];   // 32 KB

    const int z = blockIdx.z;
    const float* W = (z == 0) ? W0 : ((z == 1) ? W1 : W2);
    const float* bias = (z == 0) ? b0 : ((z == 1) ? b1 : b2);
    __hip_bfloat16* Y = (z == 0) ? Y0 : ((z == 1) ? Y1 : Y2);

    const int tid = threadIdx.x;
    const int wv = tid >> 6, lane = tid & 63;
    const int col16 = lane & 15, quad = lane >> 4;
    const int m0 = blockIdx.x * 64, n0 = blockIdx.y * 128;
    const int wr = wv >> 1, wc = wv & 1;

    // staging map (same LDS layout as gload_lds version): thread t handles
    // row trow (+32/+64/+96), LDS slot t&7, global col-slot (t&7)^(trow&7)
    const int trow = tid >> 3;
    const int scol = ((tid & 7) ^ (trow & 7)) * 8;
    const float* gx = X + (size_t)(m0 + trow) * K + scol;
    const float* gw = W + (size_t)(n0 + trow) * K + scol;
    const int wa = trow * 64 + (tid & 7) * 8;   // LDS element offset

    const int c7 = col16 & 7;
    const int so0 = ((quad)     ^ c7) * 8;
    const int so1 = ((quad + 4) ^ c7) * 8;

    float4 ra[2][2], rb[4][2];

#define QLOAD(k0)                                                            \
    {                                                                        \
        ra[0][0] = *(const float4*)(gx + (k0));                              \
        ra[0][1] = *(const float4*)(gx + (k0) + 4);                          \
        ra[1][0] = *(const float4*)(gx + (k0) + (size_t)32 * K);             \
        ra[1][1] = *(const float4*)(gx + (k0) + (size_t)32 * K + 4);         \
        rb[0][0] = *(const float4*)(gw + (k0));                              \
        rb[0][1] = *(const float4*)(gw + (k0) + 4);                          \
        rb[1][0] = *(const float4*)(gw + (k0) + (size_t)32 * K);             \
        rb[1][1] = *(const float4*)(gw + (k0) + (size_t)32 * K + 4);         \
        rb[2][0] = *(const float4*)(gw + (k0) + (size_t)64 * K);             \
        rb[2][1] = *(const float4*)(gw + (k0) + (size_t)64 * K + 4);         \
        rb[3][0] = *(const float4*)(gw + (k0) + (size_t)96 * K);             \
        rb[3][1] = *(const float4*)(gw + (k0) + (size_t)96 * K + 4);         \
    }

#define QSTORE(buf)                                                          \
    {                                                                        \
        *(bf16x8*)(As[buf] + wa)           = cvt8(ra[0][0], ra[0][1]);       \
        *(bf16x8*)(As[buf] + wa + 32 * 64) = cvt8(ra[1][0], ra[1][1]);       \
        *(bf16x8*)(Ws[buf] + wa)           = cvt8(rb[0][0], rb[0][1]);       \
        *(bf16x8*)(Ws[buf] + wa + 32 * 64) = cvt8(rb[1][0], rb[1][1]);       \
        *(bf16x8*)(Ws[buf] + wa + 64 * 64) = cvt8(rb[2][0], rb[2][1]);       \
        *(bf16x8*)(Ws[buf] + wa + 96 * 64) = cvt8(rb[3][0], rb[3][1]);       \
    }

    QLOAD(0);
    QSTORE(0);
    __syncthreads();

    f32x4 acc[8] = {};
    const int NT = K / 64;
    for (int t = 0; t < NT; ++t) {
        const int buf = t & 1;
        if (t + 1 < NT) QLOAD((t + 1) * 64);   // issue early: latency under MFMAs
        const __hip_bfloat16* ar = As[buf] + (wr * 32 + col16) * 64;
        const __hip_bfloat16* br = Ws[buf] + (wc * 64 + col16) * 64;
#pragma unroll
        for (int kh = 0; kh < 2; ++kh) {
            const int so = (kh == 0) ? so0 : so1;
            bf16x8 af[2], bfm[4];
#pragma unroll
            for (int mt = 0; mt < 2; ++mt) af[mt]  = *(const bf16x8*)(ar + mt * 16 * 64 + so);
#pragma unroll
            for (int nt = 0; nt < 4; ++nt) bfm[nt] = *(const bf16x8*)(br + nt * 16 * 64 + so);
#pragma unroll
            for (int mt = 0; mt < 2; ++mt)
#pragma unroll
                for (int nt = 0; nt < 4; ++nt)
                    acc[mt * 4 + nt] = MFMA16(af[mt], bfm[nt], acc[mt * 4 + nt]);
        }
        if (t + 1 < NT) QSTORE(buf ^ 1);       // write late, into the other buffer
        __syncthreads();
    }
#undef QLOAD
#undef QSTORE

#pragma unroll
    for (int nt = 0; nt < 4; ++nt) {
        const int n = n0 + wc * 64 + nt * 16 + col16;
        const float bv = bias[n];
#pragma unroll
        for (int mt = 0; mt < 2; ++mt) {
#pragma unroll
            for (int r = 0; r < 4; ++r) {
                const int m = m0 + wr * 32 + mt * 16 + quad * 4 + r;
                Y[(size_t)m * N + n] = __float2bfloat16(acc[mt * 4 + nt][r] + bv);
            }
        }
    }
}

// ---------------------------------------------------------------------------
// O-proj split-K=2: A (AO, bf16) via gload_lds; B (Wo) read fp32 and
// converted in staging (Wo's conversion also folded in). Same ping-pong.
// Grid (32, 8, 2) = 512 blocks. Partial 0 carries bias; summed in ln.
// ---------------------------------------------------------------------------
__global__ __launch_bounds__(256) void gemm_osplit(
    const __hip_bfloat16* __restrict__ A,
    const float* __restrict__ W,
    const float* __restrict__ bias,
    float* __restrict__ Y0, float* __restrict__ Y1,
    int M, int N, int K)
{
    __shared__ __align__(16) __hip_bfloat16 As[2][64 * 64];
    __shared__ __align__(16) __hip_bfloat16 Ws[2][128 * 64];

    const int z = blockIdx.z;
    float* Y = (z == 0) ? Y0 : Y1;
    const int kb = z * 512;

    const int tid = threadIdx.x;
    const int wv = tid >> 6, lane = tid & 63;
    const int col16 = lane & 15, quad = lane >> 4;
    const int m0 = blockIdx.x * 64, n0 = blockIdx.y * 128;
    const int wr = wv >> 1, wc = wv & 1;

    const int trow = tid >> 3;
    const int scol = ((tid & 7) ^ (trow & 7)) * 8;
    const __hip_bfloat16* ga = A + (size_t)(m0 + trow) * K + scol + kb;
    const float* gw = W + (size_t)(n0 + trow) * K + scol + kb;
    const int wofs = wv * 512;
    const int wa = trow * 64 + (tid & 7) * 8;

    const int c7 = col16 & 7;
    const int so0 = ((quad)     ^ c7) * 8;
    const int so1 = ((quad + 4) ^ c7) * 8;

    float4 rb[4][2];

#define OSTAGEA(k0, buf)                                                     \
    {                                                                        \
        gload16(ga + (k0),                  As[buf] + wofs);                 \
        gload16(ga + (k0) + (size_t)32 * K, As[buf] + wofs + 2048);          \
    }
#define OLOADB(k0)                                                           \
    {                                                                        \
        rb[0][0] = *(const float4*)(gw + (k0));                              \
        rb[0][1] = *(const float4*)(gw + (k0) + 4);                          \
        rb[1][0] = *(const float4*)(gw + (k0) + (size_t)32 * K);             \
        rb[1][1] = *(const float4*)(gw + (k0) + (size_t)32 * K + 4);         \
        rb[2][0] = *(const float4*)(gw + (k0) + (size_t)64 * K);             \
        rb[2][1] = *(const float4*)(gw + (k0) + (size_t)64 * K + 4);         \
        rb[3][0] = *(const float4*)(gw + (k0) + (size_t)96 * K);             \
        rb[3][1] = *(const float4*)(gw + (k0) + (size_t)96 * K + 4);         \
    }
#define OSTOREB(buf)                                                         \
    {                                                                        \
        *(bf16x8*)(Ws[buf] + wa)           = cvt8(rb[0][0], rb[0][1]);       \
        *(bf16x8*)(Ws[buf] + wa + 32 * 64) = cvt8(rb[1][0], rb[1][1]);       \
        *(bf16x8*)(Ws[buf] + wa + 64 * 64) = cvt8(rb[2][0], rb[2][1]);       \
        *(bf16x8*)(Ws[buf] + wa + 96 * 64) = cvt8(rb[3][0], rb[3][1]);       \
    }

    OSTAGEA(0, 0);
    OLOADB(0);
    OSTOREB(0);
    __syncthreads();

    f32x4 acc[8] = {};
    for (int t = 0; t < 8; ++t) {
        const int buf = t & 1;
        if (t + 1 < 8) {
            OSTAGEA((t + 1) * 64, buf ^ 1);
            OLOADB((t + 1) * 64);
        }
        const __hip_bfloat16* ar = As[buf] + (wr * 32 + col16) * 64;
        const __hip_bfloat16* br = Ws[buf] + (wc * 64 + col16) * 64;
#pragma unroll
        for (int kh = 0; kh < 2; ++kh) {
            const int so = (kh == 0) ? so0 : so1;
            bf16x8 af[2], bfm[4];
#pragma unroll
            for (int mt = 0; mt < 2; ++mt) af[mt]  = *(const bf16x8*)(ar + mt * 16 * 64 + so);
#pragma unroll
            for (int nt = 0; nt < 4; ++nt) bfm[nt] = *(const bf16x8*)(br + nt * 16 * 64 + so);
#pragma unroll
            for (int mt = 0; mt < 2; ++mt)
#pragma unroll
                for (int nt = 0; nt < 4; ++nt)
                    acc[mt * 4 + nt] = MFMA16(af[mt], bfm[nt], acc[mt * 4 + nt]);
        }
        if (t + 1 < 8) OSTOREB(buf ^ 1);
        __syncthreads();
    }
#undef OSTAGEA
#undef OLOADB
#undef OSTOREB

#pragma unroll
    for (int nt = 0; nt < 4; ++nt) {
        const int n = n0 + wc * 64 + nt * 16 + col16;
        const float bv = (z == 0) ? bias[n] : 0.0f;
#pragma unroll
        for (int mt = 0; mt < 2; ++mt) {
#pragma unroll
            for (int r = 0; r < 4; ++r) {
                const int m = m0 + wr * 32 + mt * 16 + quad * 4 + r;
                Y[(size_t)m * N + n] = acc[mt * 4 + nt][r] + bv;
            }
        }
    }
}

// ---------------------------------------------------------------------------
// Attention — R8/R10 version unchanged (swapped QK^T + Vt dbuf, 1 barrier/iter).
// ---------------------------------------------------------------------------
__global__ __launch_bounds__(256) void attn_kernel(
    const __hip_bfloat16* __restrict__ Q,
    const __hip_bfloat16* __restrict__ K,
    const __hip_bfloat16* __restrict__ V,
    const float* __restrict__ alpha, const float* __restrict__ phi,
    const float* __restrict__ temperature,
    __hip_bfloat16* __restrict__ AO)
{
    __shared__ __align__(16) char smem[2 * 18432 + 512];
    __hip_bfloat16* VtBase = (__hip_bfloat16*)smem;          // [2][2half][64*72]
    float* Ocomb = (float*)smem;                 // [2][16][68] (epilogue reuse)
    float* Dl    = (float*)(smem + 2 * 18432);   // [2][32]

    const int tid = threadIdx.x;
    const int wv = tid >> 6, lane = tid & 63;
    const int col16 = lane & 15, quad = lane >> 4;
    const int g = wv & 1, half = wv >> 1;

    const int bh = blockIdx.y, b = bh >> 4, h = bh & 15;
    const int i0 = blockIdx.x * 32 + g * 16;
    const size_t base = ((size_t)b * SEQ) * DIM + (size_t)h * HD;

    const float tempv = fabsf(temperature[0]) + 0.1f;
    const float simscale = 1.0f / (8.0f * tempv);
    const float freqs[5] = {31.0f, 37.0f, 41.0f, 43.0f, 47.0f};

    // degree-7 poly of log2e*score(s); w = rcp(1+exp2(-poly(s)))  [R5-validated]
    float p[8] = {0.f, 0.f, 0.f, 0.f, 0.f, 0.f, 0.f, 0.f};
#pragma unroll
    for (int f = 0; f < 5; ++f) {
        const float a  = alpha[h * 5 + f] * 1.44269504089f;  // fold log2(e)
        const float ph = phi[h * 5 + f];
        const float sp = __sinf(ph), cp = __cosf(ph);
        const float c  = 6.28318530718f * simscale / freqs[f];
        const float c2 = c * c, c3 = c2 * c, c4 = c2 * c2;
        const float c5 = c4 * c, c6 = c4 * c2, c7 = c4 * c3;
        p[0] += a * sp;
        p[1] += a * cp * c;
        p[2] -= a * sp * c2 * 0.5f;
        p[3] -= a * cp * c3 * (1.0f / 6.0f);
        p[4] += a * sp * c4 * (1.0f / 24.0f);
        p[5] += a * cp * c5 * (1.0f / 120.0f);
        p[6] -= a * sp * c6 * (1.0f / 720.0f);
        p[7] -= a * cp * c7 * (1.0f / 5040.0f);
    }

    const __hip_bfloat16* qrow = Q + base + (size_t)(i0 + col16) * DIM + quad * 8;
    const bf16x8 qa0 = *(const bf16x8*)(qrow);
    const bf16x8 qa1 = *(const bf16x8*)(qrow + 32);

    const __hip_bfloat16* kbase = K + base + (size_t)col16 * DIM + quad * 8;

    const int tl = tid & 127;
    const int sc0 = (tl & 7) * 8;
    const int sx  = tl & 7;
    const int jj0 = (tl >> 3) * 2;
    // column permutation pi(j) within 32-j sub-block (j-pair keeps r,r+1 adjacent)
    const int pu = (jj0 >> 4) & 1, pqs = (jj0 >> 2) & 3, pr = jj0 & 3;
    const int col0 = ((pqs ^ (pu << 1)) << 3) + (pu << 2) + pr;   // pi(jj0)
    __hip_bfloat16* VtH = VtBase + half * 4608;    // buf stride = 9216 elements
    __hip_bfloat16* rowp[8];
#pragma unroll
    for (int e = 0; e < 8; ++e) rowp[e] = VtH + (sc0 + (e ^ sx)) * 72;

    const __hip_bfloat16* vrd[4];
#pragma unroll
    for (int t = 0; t < 4; ++t)
        vrd[t] = VtH + swz(t * 16 + col16) * 72 + quad * 8;

    f32x4 o[4] = {};
    float denomL = 0.f;

    bf16x8 vr[2][2];   // prefetched V regs (V(j) for next pack)
    bf16x8 kf[4][2];   // prefetched K frags

#define LOADV(jt)                                                              \
    {                                                                          \
        const int jv = half * 512 + (jt) * 64;                                 \
        _Pragma("unroll")                                                      \
        for (int s = 0; s < 2; ++s) {                                          \
            const __hip_bfloat16* vp =                                         \
                V + base + (size_t)(jv + jj0 + 32 * s) * DIM + sc0;            \
            vr[s][0] = *(const bf16x8*)(vp);                                   \
            vr[s][1] = *(const bf16x8*)(vp + DIM);                             \
        }                                                                      \
    }

#define PACKV(pofs)                                                            \
    {                                                                          \
        _Pragma("unroll")                                                      \
        for (int s = 0; s < 2; ++s) {                                          \
            _Pragma("unroll")                                                  \
            for (int e = 0; e < 8; ++e) {                                      \
                unsigned pk = ((unsigned)(unsigned short)vr[s][0][e]) |        \
                              (((unsigned)(unsigned short)vr[s][1][e]) << 16); \
                *(unsigned*)(rowp[e] + (pofs) + col0 + 32 * s) = pk;           \
            }                                                                  \
        }                                                                      \
    }

    // prologue: V(0) -> buf0; preload V(1), K(0)
    LOADV(0);
    PACKV(0);
    LOADV(1);
    {
        const int j0 = half * 512;
#pragma unroll
        for (int u = 0; u < 4; ++u) {
            const __hip_bfloat16* kp = kbase + (size_t)(j0 + u * 16) * DIM;
            kf[u][0] = *(const bf16x8*)(kp);
            kf[u][1] = *(const bf16x8*)(kp + 32);
        }
    }
    __syncthreads();   // buf0 visible

    for (int it = 0; it < 8; ++it) {
        const int cur = it & 1;
        if (it < 7) PACKV((cur ^ 1) * 9216);
        if (it < 6) LOADV(it + 2);

        // swapped QK^T: lane holds S[j = u*16 + quad*4 + r][i = col16]
        f32x4 sa4[4];
        __builtin_amdgcn_s_setprio(1);
#pragma unroll
        for (int u = 0; u < 4; ++u) {
            f32x4 zz = {};
            zz = MFMA16(kf[u][0], qa0, zz);
            zz = MFMA16(kf[u][1], qa1, zz);
            sa4[u] = zz;
        }
        __builtin_amdgcn_s_setprio(0);

        if (it < 7) {
            const int j1 = half * 512 + (it + 1) * 64;
#pragma unroll
            for (int u = 0; u < 4; ++u) {
                const __hip_bfloat16* kp = kbase + (size_t)(j1 + u * 16) * DIM;
                kf[u][0] = *(const bf16x8*)(kp);
                kf[u][1] = *(const bf16x8*)(kp + 32);
            }
        }

#pragma unroll
        for (int sub = 0; sub < 2; ++sub) {
            float w[2][4];
#pragma unroll
            for (int s2 = 0; s2 < 2; ++s2) {
                const int u = sub * 2 + s2;
#pragma unroll
                for (int r = 0; r < 4; ++r) {
                    const float sv = sa4[u][r];
                    float sc = fmaf(sv, p[7], p[6]);
                    sc = fmaf(sv, sc, p[5]);
                    sc = fmaf(sv, sc, p[4]);
                    sc = fmaf(sv, sc, p[3]);
                    sc = fmaf(sv, sc, p[2]);
                    sc = fmaf(sv, sc, p[1]);
                    sc = fmaf(sv, sc, p[0]);
                    const float ww = FAST_RCP(1.0f + EXP2F(-sc));
                    denomL += ww;
                    w[s2][r] = ww;
                }
            }
            // in-register P fragment: u'=0 stays, u'=1 crosses lane^32
            const unsigned pk00 = pack2bf(w[0][0], w[0][1]);
            const unsigned pk01 = pack2bf(w[0][2], w[0][3]);
            const unsigned pk10 = pack2bf(w[1][0], w[1][1]);
            const unsigned pk11 = pack2bf(w[1][2], w[1][3]);
            const unsigned sw0 = (unsigned)__shfl_xor((int)pk10, 32);
            const unsigned sw1 = (unsigned)__shfl_xor((int)pk11, 32);
            union { unsigned d[4]; bf16x8 v; } pu8;
            pu8.d[0] = pk00; pu8.d[1] = pk01; pu8.d[2] = sw0; pu8.d[3] = sw1;
            const bf16x8 pa = pu8.v;

            __builtin_amdgcn_s_setprio(1);
#pragma unroll
            for (int t = 0; t < 4; ++t) {
                bf16x8 vb = *(const bf16x8*)(vrd[t] + cur * 9216 + 32 * sub);
                o[t] = MFMA16(pa, vb, o[t]);
            }
            __builtin_amdgcn_s_setprio(0);
        }
        __syncthreads();   // Vt[cur^1] packed & visible; Vt[cur] reads done
    }
#undef LOADV
#undef PACKV

    // denom: lane holds partial for i=col16 over its js; reduce across quads
    denomL += __shfl_xor(denomL, 16);
    denomL += __shfl_xor(denomL, 32);

    if (quad == 0) Dl[half * 32 + g * 16 + col16] = denomL;
    if (half == 1) {
#pragma unroll
        for (int t = 0; t < 4; ++t)
#pragma unroll
            for (int r = 0; r < 4; ++r)
                Ocomb[(g * 16 + quad * 4 + r) * 68 + t * 16 + col16] = o[t][r];
    }
    __syncthreads();
    if (half == 0) {
        float dn[4];
#pragma unroll
        for (int r = 0; r < 4; ++r)
            dn[r] = Dl[g * 16 + quad * 4 + r] + Dl[32 + g * 16 + quad * 4 + r] + 1e-10f;
#pragma unroll
        for (int t = 0; t < 4; ++t) {
#pragma unroll
            for (int r = 0; r < 4; ++r) {
                const float val =
                    (o[t][r] + Ocomb[(g * 16 + quad * 4 + r) * 68 + t * 16 + col16]) / dn[r];
                const size_t row = (size_t)b * SEQ + i0 + quad * 4 + r;
                AO[row * DIM + h * HD + t * 16 + col16] = __float2bfloat16(val);
            }
        }
    }
}

// ---------------------------------------------------------------------------
// LayerNorm over last dim (1024), sums the two split-K partials of O-proj.
// ---------------------------------------------------------------------------
__global__ __launch_bounds__(256) void ln_kernel(
    const float* __restrict__ Yp0,
    const float* __restrict__ Yp1,
    const float* __restrict__ gamma,
    const float* __restrict__ beta,
    float* __restrict__ out)
{
    const int row = blockIdx.x;
    const float* y0 = Yp0 + (size_t)row * DIM;
    const float* y1 = Yp1 + (size_t)row * DIM;

    float v[4];
    float s = 0.f, s2 = 0.f;
#pragma unroll
    for (int e = 0; e < 4; ++e) {
        const int idx = threadIdx.x + e * 256;
        v[e] = y0[idx] + y1[idx];
        s += v[e];
        s2 += v[e] * v[e];
    }
#pragma unroll
    for (int off = 1; off < 64; off <<= 1) {
        s  += __shfl_xor(s, off);
        s2 += __shfl_xor(s2, off);
    }
    __shared__ float ps[4], ps2[4];
    const int wave = threadIdx.x >> 6;
    if ((threadIdx.x & 63) == 0) { ps[wave] = s; ps2[wave] = s2; }
    __syncthreads();
    s  = ps[0] + ps[1] + ps[2] + ps[3];
    s2 = ps2[0] + ps2[1] + ps2[2] + ps2[3];

    const float mu   = s * (1.0f / DIM);
    const float var  = s2 * (1.0f / DIM) - mu * mu;
    const float rstd = rsqrtf(var + 1e-5f);

#pragma unroll
    for (int e = 0; e < 4; ++e) {
        const int idx = threadIdx.x + e * 256;
        out[(size_t)row * DIM + idx] =
            (v[e] - mu) * rstd * gamma[idx] + beta[idx];
    }
}

// ---------------------------------------------------------------------------
extern "C" void kernel_launch(void* const* d_in, const int* in_sizes, int n_in,
                              void* d_out, int out_size, void* d_ws, size_t ws_size,
                              hipStream_t stream)
{
    const float* x     = (const float*)d_in[0];
    const float* Wq    = (const float*)d_in[1];
    const float* bq    = (const float*)d_in[2];
    const float* Wk    = (const float*)d_in[3];
    const float* bk    = (const float*)d_in[4];
    const float* Wv    = (const float*)d_in[5];
    const float* bv    = (const float*)d_in[6];
    const float* Wo    = (const float*)d_in[7];
    const float* bo    = (const float*)d_in[8];
    const float* alpha = (const float*)d_in[9];
    const float* phi   = (const float*)d_in[10];
    const float* temp  = (const float*)d_in[11];
    const float* gamma = (const float*)d_in[12];
    const float* beta  = (const float*)d_in[13];

    float* out = (float*)d_out;

    const int B = 2;
    const int M = B * SEQ;                 // 2048

    // ws layout (MB): conversion buffers eliminated (fused into GEMM staging).
    //   [12,16) Qb   [16,20) Kb   [20,24) Vb   [24,28) AO   (bf16)
    //   Yp0 (fp32 8MB) at [0,8) ; Yp1 (fp32 8MB) aliases [12,20) — Qb/Kb dead
    //   by O-proj time.
    char* wsb = (char*)d_ws;
    __hip_bfloat16* Qb  = (__hip_bfloat16*)(wsb + (12u << 20));
    __hip_bfloat16* Kb  = (__hip_bfloat16*)(wsb + (16u << 20));
    __hip_bfloat16* Vb  = (__hip_bfloat16*)(wsb + (20u << 20));
    __hip_bfloat16* AO  = (__hip_bfloat16*)(wsb + (24u << 20));
    float*          Yp0 = (float*)(wsb + 0);
    float*          Yp1 = (float*)(wsb + (12u << 20));

    hipLaunchKernelGGL(gemm_qkv, dim3(M / 64, DIM / 128, 3), dim3(256), 0, stream,
                       x, Wq, Wk, Wv, bq, bk, bv, Qb, Kb, Vb, M, DIM, DIM);

    hipLaunchKernelGGL(attn_kernel, dim3(SEQ / 32, B * NH), dim3(256), 0, stream,
                       Qb, Kb, Vb, alpha, phi, temp, AO);

    hipLaunchKernelGGL(gemm_osplit, dim3(M / 64, DIM / 128, 2), dim3(256), 0, stream,
                       AO, Wo, bo, Yp0, Yp1, M, DIM, DIM);

    hipLaunchKernelGGL(ln_kernel, dim3(M), dim3(256), 0, stream,
                       Yp0, Yp1, gamma, beta, out);
}

// Round 13
// 172.751 us; speedup vs baseline: 1.0437x; 1.0437x over previous
//
#include <hip/hip_runtime.h>
#include <hip/hip_bf16.h>

typedef short bf16x8 __attribute__((ext_vector_type(8)));
typedef float f32x4 __attribute__((ext_vector_type(4)));

#define MFMA16(a, b, c) __builtin_amdgcn_mfma_f32_16x16x32_bf16(a, b, c, 0, 0, 0)

static constexpr int SEQ = 1024;
static constexpr int DIM = 1024;
static constexpr int NH = 16;
static constexpr int HD = 64;

#if __has_builtin(__builtin_amdgcn_rcpf)
#define FAST_RCP(x) __builtin_amdgcn_rcpf(x)
#else
#define FAST_RCP(x) (1.0f / (x))
#endif

#if __has_builtin(__builtin_amdgcn_exp2f)
#define EXP2F(x) __builtin_amdgcn_exp2f(x)
#else
#define EXP2F(x) exp2f(x)
#endif

__device__ __forceinline__ int swz(int r) { return r ^ (r >> 3); } // row-XOR bank swizzle

// async global->LDS, 16B per lane. lds ptr must be wave-uniform (HW adds lane*16).
__device__ __forceinline__ void gload16(const __hip_bfloat16* g, __hip_bfloat16* l)
{
    typedef const __attribute__((address_space(1))) unsigned GU;
    typedef __attribute__((address_space(3))) unsigned LU;
    __builtin_amdgcn_global_load_lds((GU*)g, (LU*)l, 16, 0, 0);
}

__device__ __forceinline__ unsigned pack2bf(float a, float b)
{
    union { __hip_bfloat16 h; unsigned short u; } ca, cb;
    ca.h = __float2bfloat16(a); cb.h = __float2bfloat16(b);
    return (unsigned)ca.u | ((unsigned)cb.u << 16);
}

// ---------------------------------------------------------------------------
// fused fp32->bf16 conversion for all 5 tensors (grid.y selects region)
// ---------------------------------------------------------------------------
__global__ __launch_bounds__(256) void cvt_all(
    const float* __restrict__ x,  const float* __restrict__ wq,
    const float* __restrict__ wk, const float* __restrict__ wv,
    const float* __restrict__ wo,
    __hip_bfloat16* __restrict__ xb,  __hip_bfloat16* __restrict__ wqb,
    __hip_bfloat16* __restrict__ wkb, __hip_bfloat16* __restrict__ wvb,
    __hip_bfloat16* __restrict__ wob)
{
    const int reg = blockIdx.y;
    const float* src; __hip_bfloat16* dst; int n;
    if      (reg == 0) { src = x;  dst = xb;  n = 2 * SEQ * DIM; }
    else if (reg == 1) { src = wq; dst = wqb; n = DIM * DIM; }
    else if (reg == 2) { src = wk; dst = wkb; n = DIM * DIM; }
    else if (reg == 3) { src = wv; dst = wvb; n = DIM * DIM; }
    else               { src = wo; dst = wob; n = DIM * DIM; }
    const int i = (blockIdx.x * 256 + threadIdx.x) * 4;
    if (i < n) {
        float4 v = *(const float4*)(src + i);
        __hip_bfloat16 t[4];
        t[0] = __float2bfloat16(v.x); t[1] = __float2bfloat16(v.y);
        t[2] = __float2bfloat16(v.z); t[3] = __float2bfloat16(v.w);
        *(ushort4*)(dst + i) = *(ushort4*)t;
    }
}

// ---------------------------------------------------------------------------
// GEMM 64x128 tile, BK=64, gload_lds + XOR swizzle + single-barrier dbuf
// (exact R8 version, best-measured).
// ---------------------------------------------------------------------------
__global__ __launch_bounds__(256) void gemm_qkv(
    const __hip_bfloat16* __restrict__ A,
    const __hip_bfloat16* __restrict__ W0, const __hip_bfloat16* __restrict__ W1,
    const __hip_bfloat16* __restrict__ W2,
    const float* __restrict__ b0, const float* __restrict__ b1,
    const float* __restrict__ b2,
    __hip_bfloat16* __restrict__ Y0, __hip_bfloat16* __restrict__ Y1,
    __hip_bfloat16* __restrict__ Y2,
    int M, int N, int K)
{
    __shared__ __align__(16) __hip_bfloat16 As[2][64 * 64];
    __shared__ __align__(16) __hip_bfloat16 Ws[2][128 * 64];

    const int z = blockIdx.z;
    const __hip_bfloat16* W = (z == 0) ? W0 : ((z == 1) ? W1 : W2);
    const float* bias = (z == 0) ? b0 : ((z == 1) ? b1 : b2);
    __hip_bfloat16* Y = (z == 0) ? Y0 : ((z == 1) ? Y1 : Y2);

    const int tid = threadIdx.x;
    const int wv = tid >> 6, lane = tid & 63;
    const int col16 = lane & 15, quad = lane >> 4;
    const int m0 = blockIdx.x * 64, n0 = blockIdx.y * 128;
    const int wr = wv >> 1, wc = wv & 1;

    const int scol = ((tid & 7) ^ ((tid >> 3) & 7)) * 8;
    const __hip_bfloat16* ga = A + (size_t)(m0 + (tid >> 3)) * K + scol;
    const __hip_bfloat16* gb = W + (size_t)(n0 + (tid >> 3)) * K + scol;
    const int wofs = wv * 512;

    const int c7 = col16 & 7;
    const int so0 = ((quad)     ^ c7) * 8;
    const int so1 = ((quad + 4) ^ c7) * 8;

#define QKV_STAGE(k0, buf)                                         \
    {                                                              \
        __hip_bfloat16* lA = As[buf] + wofs;                       \
        __hip_bfloat16* lB = Ws[buf] + wofs;                       \
        gload16(ga + (k0),                    lA);                 \
        gload16(ga + (k0) + (size_t)32 * K,   lA + 2048);          \
        gload16(gb + (k0),                    lB);                 \
        gload16(gb + (k0) + (size_t)32 * K,   lB + 2048);          \
        gload16(gb + (k0) + (size_t)64 * K,   lB + 4096);          \
        gload16(gb + (k0) + (size_t)96 * K,   lB + 6144);          \
    }

    QKV_STAGE(0, 0);
    __syncthreads();

    f32x4 acc[8] = {};
    const int NT = K / 64;
    for (int t = 0; t < NT; ++t) {
        const int buf = t & 1;
        if (t + 1 < NT) QKV_STAGE((t + 1) * 64, buf ^ 1);
        const __hip_bfloat16* ar = As[buf] + (wr * 32 + col16) * 64;
        const __hip_bfloat16* br = Ws[buf] + (wc * 64 + col16) * 64;
#pragma unroll
        for (int kh = 0; kh < 2; ++kh) {
            const int so = (kh == 0) ? so0 : so1;
            bf16x8 af[2], bfm[4];
#pragma unroll
            for (int mt = 0; mt < 2; ++mt) af[mt]  = *(const bf16x8*)(ar + mt * 16 * 64 + so);
#pragma unroll
            for (int nt = 0; nt < 4; ++nt) bfm[nt] = *(const bf16x8*)(br + nt * 16 * 64 + so);
#pragma unroll
            for (int mt = 0; mt < 2; ++mt)
#pragma unroll
                for (int nt = 0; nt < 4; ++nt)
                    acc[mt * 4 + nt] = MFMA16(af[mt], bfm[nt], acc[mt * 4 + nt]);
        }
        __syncthreads();
    }
#undef QKV_STAGE

#pragma unroll
    for (int nt = 0; nt < 4; ++nt) {
        const int n = n0 + wc * 64 + nt * 16 + col16;
        const float bv = bias[n];
#pragma unroll
        for (int mt = 0; mt < 2; ++mt) {
#pragma unroll
            for (int r = 0; r < 4; ++r) {
                const int m = m0 + wr * 32 + mt * 16 + quad * 4 + r;
                Y[(size_t)m * N + n] = __float2bfloat16(acc[mt * 4 + nt][r] + bv);
            }
        }
    }
}

// ---------------------------------------------------------------------------
// O-proj split-K=2, same single-barrier dbuf structure (exact R8 version).
// ---------------------------------------------------------------------------
__global__ __launch_bounds__(256) void gemm_osplit(
    const __hip_bfloat16* __restrict__ A,
    const __hip_bfloat16* __restrict__ W,
    const float* __restrict__ bias,
    float* __restrict__ Y0, float* __restrict__ Y1,
    int M, int N, int K)
{
    __shared__ __align__(16) __hip_bfloat16 As[2][64 * 64];
    __shared__ __align__(16) __hip_bfloat16 Ws[2][128 * 64];

    const int z = blockIdx.z;
    float* Y = (z == 0) ? Y0 : Y1;
    const int kb = z * 512;

    const int tid = threadIdx.x;
    const int wv = tid >> 6, lane = tid & 63;
    const int col16 = lane & 15, quad = lane >> 4;
    const int m0 = blockIdx.x * 64, n0 = blockIdx.y * 128;
    const int wr = wv >> 1, wc = wv & 1;

    const int scol = ((tid & 7) ^ ((tid >> 3) & 7)) * 8;
    const __hip_bfloat16* ga = A + (size_t)(m0 + (tid >> 3)) * K + scol + kb;
    const __hip_bfloat16* gb = W + (size_t)(n0 + (tid >> 3)) * K + scol + kb;
    const int wofs = wv * 512;

    const int c7 = col16 & 7;
    const int so0 = ((quad)     ^ c7) * 8;
    const int so1 = ((quad + 4) ^ c7) * 8;

#define OS_STAGE(k0, buf)                                          \
    {                                                              \
        __hip_bfloat16* lA = As[buf] + wofs;                       \
        __hip_bfloat16* lB = Ws[buf] + wofs;                       \
        gload16(ga + (k0),                    lA);                 \
        gload16(ga + (k0) + (size_t)32 * K,   lA + 2048);          \
        gload16(gb + (k0),                    lB);                 \
        gload16(gb + (k0) + (size_t)32 * K,   lB + 2048);          \
        gload16(gb + (k0) + (size_t)64 * K,   lB + 4096);          \
        gload16(gb + (k0) + (size_t)96 * K,   lB + 6144);          \
    }

    OS_STAGE(0, 0);
    __syncthreads();

    f32x4 acc[8] = {};
    for (int t = 0; t < 8; ++t) {
        const int buf = t & 1;
        if (t + 1 < 8) OS_STAGE((t + 1) * 64, buf ^ 1);
        const __hip_bfloat16* ar = As[buf] + (wr * 32 + col16) * 64;
        const __hip_bfloat16* br = Ws[buf] + (wc * 64 + col16) * 64;
#pragma unroll
        for (int kh = 0; kh < 2; ++kh) {
            const int so = (kh == 0) ? so0 : so1;
            bf16x8 af[2], bfm[4];
#pragma unroll
            for (int mt = 0; mt < 2; ++mt) af[mt]  = *(const bf16x8*)(ar + mt * 16 * 64 + so);
#pragma unroll
            for (int nt = 0; nt < 4; ++nt) bfm[nt] = *(const bf16x8*)(br + nt * 16 * 64 + so);
#pragma unroll
            for (int mt = 0; mt < 2; ++mt)
#pragma unroll
                for (int nt = 0; nt < 4; ++nt)
                    acc[mt * 4 + nt] = MFMA16(af[mt], bfm[nt], acc[mt * 4 + nt]);
        }
        __syncthreads();
    }
#undef OS_STAGE

#pragma unroll
    for (int nt = 0; nt < 4; ++nt) {
        const int n = n0 + wc * 64 + nt * 16 + col16;
        const float bv = (z == 0) ? bias[n] : 0.0f;
#pragma unroll
        for (int mt = 0; mt < 2; ++mt) {
#pragma unroll
            for (int r = 0; r < 4; ++r) {
                const int m = m0 + wr * 32 + mt * 16 + quad * 4 + r;
                Y[(size_t)m * N + n] = acc[mt * 4 + nt][r] + bv;
            }
        }
    }
}

// ---------------------------------------------------------------------------
// Attention — barrier-free wave-private structure (R12 concept, LAYOUT FIXED):
//   tile is [64][72] per wave (stride 72, col(j) spans 0..63 + pad);
//   write row = swz(d) = sc0+ch*32 + (e ^ (sx ^ (4*ch)))   [sx = lane&3]
//   read  row = swz(t*16+col16)                            [R8 invariant]
// Wave w owns js [w*256,(w+1)*256); ZERO main-loop barriers. PV A-frag fully
// in-lane: lane's w[u][r] = slot e=(u&1)*4+r, s=u>>1 (verified end-to-end).
// One barrier before O-combine (waves 1-3 stash f32 partials in own Vt).
// ---------------------------------------------------------------------------
__global__ __launch_bounds__(256) void attn_kernel(
    const __hip_bfloat16* __restrict__ Q,
    const __hip_bfloat16* __restrict__ K,
    const __hip_bfloat16* __restrict__ V,
    const float* __restrict__ alpha, const float* __restrict__ phi,
    const float* __restrict__ temperature,
    __hip_bfloat16* __restrict__ AO)
{
    __shared__ __align__(16) __hip_bfloat16 Vt[4 * 4608];   // 4 waves x [64][72]
    __shared__ float Dl[4][16];

    const int tid = threadIdx.x;
    const int wv = tid >> 6, lane = tid & 63;
    const int col16 = lane & 15, quad = lane >> 4;

    const int bh = blockIdx.y, b = bh >> 4, h = bh & 15;
    const int i0 = blockIdx.x * 16;
    const size_t base = ((size_t)b * SEQ) * DIM + (size_t)h * HD;

    const float tempv = fabsf(temperature[0]) + 0.1f;
    const float simscale = 1.0f / (8.0f * tempv);
    const float freqs[5] = {31.0f, 37.0f, 41.0f, 43.0f, 47.0f};

    // degree-7 poly of log2e*score(s); w = rcp(1+exp2(-poly(s)))  [R5-validated]
    float p[8] = {0.f, 0.f, 0.f, 0.f, 0.f, 0.f, 0.f, 0.f};
#pragma unroll
    for (int f = 0; f < 5; ++f) {
        const float a  = alpha[h * 5 + f] * 1.44269504089f;  // fold log2(e)
        const float ph = phi[h * 5 + f];
        const float sp = __sinf(ph), cp = __cosf(ph);
        const float c  = 6.28318530718f * simscale / freqs[f];
        const float c2 = c * c, c3 = c2 * c, c4 = c2 * c2;
        const float c5 = c4 * c, c6 = c4 * c2, c7 = c4 * c3;
        p[0] += a * sp;
        p[1] += a * cp * c;
        p[2] -= a * sp * c2 * 0.5f;
        p[3] -= a * cp * c3 * (1.0f / 6.0f);
        p[4] += a * sp * c4 * (1.0f / 24.0f);
        p[5] += a * cp * c5 * (1.0f / 120.0f);
        p[6] -= a * sp * c6 * (1.0f / 720.0f);
        p[7] -= a * cp * c7 * (1.0f / 5040.0f);
    }

    const __hip_bfloat16* qrow = Q + base + (size_t)(i0 + col16) * DIM + quad * 8;
    const bf16x8 qa0 = *(const bf16x8*)(qrow);
    const bf16x8 qa1 = *(const bf16x8*)(qrow + 32);

    const __hip_bfloat16* kbase = K + base + (size_t)col16 * DIM + quad * 8;
    const int jbase = wv * 256;                       // wave's j-range

    // V staging (wave-private): lane -> j-pair jj0, d-chunks sc0(+32)
    const int jj0 = (lane >> 2) * 2;                  // 0,2,..,30
    const int sx  = lane & 3;
    const int sc0 = sx * 8;
    // col(j) = ((j>>2)&3)*8 + ((j>>4)&1)*4 + (j&3)  (+32 for j>=32)
    const int col0 = ((jj0 >> 2) & 3) * 8 + ((jj0 >> 4) & 1) * 4 + (jj0 & 3);
    __hip_bfloat16* VtW = Vt + wv * 4608;             // [64][72]
    // write row for d = sc0 + ch*32 + e is swz(d) = sc0 + ch*32 + (e^(sx^(4ch)))
    __hip_bfloat16* rowp[8];                          // ch=0 rows; ch=1 via [e^4]+32*72
#pragma unroll
    for (int e = 0; e < 8; ++e) rowp[e] = VtW + (sc0 + (e ^ sx)) * 72;

    const __hip_bfloat16* vrd[4];
#pragma unroll
    for (int t = 0; t < 4; ++t)
        vrd[t] = VtW + swz(t * 16 + col16) * 72 + quad * 8;

    f32x4 o[4] = {};
    float denomL = 0.f;

    bf16x8 kf[4][2];
#pragma unroll
    for (int u = 0; u < 4; ++u) {
        const __hip_bfloat16* kp = kbase + (size_t)(jbase + u * 16) * DIM;
        kf[u][0] = *(const bf16x8*)(kp);
        kf[u][1] = *(const bf16x8*)(kp + 32);
    }

    for (int it = 0; it < 4; ++it) {
        const int jv = jbase + it * 64;

        // issue this iter's V loads early (latency hides under QK^T + poly)
        bf16x8 vr[2][2][2];   // [jgrp][chunk][row01]
#pragma unroll
        for (int jg = 0; jg < 2; ++jg) {
            const __hip_bfloat16* vp =
                V + base + (size_t)(jv + jj0 + jg * 32) * DIM + sc0;
#pragma unroll
            for (int ch = 0; ch < 2; ++ch) {
                vr[jg][ch][0] = *(const bf16x8*)(vp + ch * 32);
                vr[jg][ch][1] = *(const bf16x8*)(vp + DIM + ch * 32);
            }
        }

        // swapped QK^T: lane holds S[j = u*16 + quad*4 + r][i = col16]
        f32x4 sa[4];
        __builtin_amdgcn_s_setprio(1);
#pragma unroll
        for (int u = 0; u < 4; ++u) {
            f32x4 zz = {};
            zz = MFMA16(kf[u][0], qa0, zz);
            zz = MFMA16(kf[u][1], qa1, zz);
            sa[u] = zz;
        }
        __builtin_amdgcn_s_setprio(0);

        // K prefetch for next iter (kf dead after QK^T)
        if (it < 3) {
            const int j1 = jbase + (it + 1) * 64;
#pragma unroll
            for (int u = 0; u < 4; ++u) {
                const __hip_bfloat16* kp = kbase + (size_t)(j1 + u * 16) * DIM;
                kf[u][0] = *(const bf16x8*)(kp);
                kf[u][1] = *(const bf16x8*)(kp + 32);
            }
        }

        // poly + sigmoid on all 16 scores
        float w[4][4];
#pragma unroll
        for (int u = 0; u < 4; ++u) {
#pragma unroll
            for (int r = 0; r < 4; ++r) {
                const float sv = sa[u][r];
                float sc = fmaf(sv, p[7], p[6]);
                sc = fmaf(sv, sc, p[5]);
                sc = fmaf(sv, sc, p[4]);
                sc = fmaf(sv, sc, p[3]);
                sc = fmaf(sv, sc, p[2]);
                sc = fmaf(sv, sc, p[1]);
                sc = fmaf(sv, sc, p[0]);
                const float ww = FAST_RCP(1.0f + EXP2F(-sc));
                denomL += ww;
                w[u][r] = ww;
            }
        }

        // pack V into the wave-private Vt: row = swz(d), col = col(j)
#pragma unroll
        for (int jg = 0; jg < 2; ++jg) {
#pragma unroll
            for (int e = 0; e < 8; ++e) {
                unsigned pk0 =
                    ((unsigned)(unsigned short)vr[jg][0][0][e]) |
                    (((unsigned)(unsigned short)vr[jg][0][1][e]) << 16);
                *(unsigned*)(rowp[e] + col0 + jg * 32) = pk0;       // ch=0
                unsigned pk1 =
                    ((unsigned)(unsigned short)vr[jg][1][0][e]) |
                    (((unsigned)(unsigned short)vr[jg][1][1][e]) << 16);
                *(unsigned*)(rowp[e ^ 4] + 32 * 72 + col0 + jg * 32) = pk1; // ch=1
            }
        }

        // PV: A-fragment fully in-lane (no shuffles)
#pragma unroll
        for (int s = 0; s < 2; ++s) {
            union { unsigned d[4]; bf16x8 v; } pu8;
            pu8.d[0] = pack2bf(w[2 * s][0], w[2 * s][1]);
            pu8.d[1] = pack2bf(w[2 * s][2], w[2 * s][3]);
            pu8.d[2] = pack2bf(w[2 * s + 1][0], w[2 * s + 1][1]);
            pu8.d[3] = pack2bf(w[2 * s + 1][2], w[2 * s + 1][3]);
            const bf16x8 pa = pu8.v;
            __builtin_amdgcn_s_setprio(1);
#pragma unroll
            for (int t = 0; t < 4; ++t) {
                bf16x8 vb = *(const bf16x8*)(vrd[t] + s * 32);
                o[t] = MFMA16(pa, vb, o[t]);
            }
            __builtin_amdgcn_s_setprio(0);
        }
    }

    // wave-local denom for i=col16 over this wave's 256 js
    denomL += __shfl_xor(denomL, 16);
    denomL += __shfl_xor(denomL, 32);
    if (quad == 0) Dl[wv][col16] = denomL;

    // waves 1-3 stash O-partials into their OWN dead Vt region (fp32 [16][68])
    if (wv > 0) {
        float* Oc = (float*)(Vt + wv * 4608);
#pragma unroll
        for (int t = 0; t < 4; ++t)
#pragma unroll
            for (int r = 0; r < 4; ++r)
                Oc[(quad * 4 + r) * 68 + t * 16 + col16] = o[t][r];
    }
    __syncthreads();   // the ONLY block-wide barrier
    if (wv == 0) {
        float dn[4];
#pragma unroll
        for (int r = 0; r < 4; ++r)
            dn[r] = Dl[0][quad * 4 + r] + Dl[1][quad * 4 + r] +
                    Dl[2][quad * 4 + r] + Dl[3][quad * 4 + r] + 1e-10f;
#pragma unroll
        for (int t = 0; t < 4; ++t) {
#pragma unroll
            for (int r = 0; r < 4; ++r) {
                float val = o[t][r];
#pragma unroll
                for (int ww = 1; ww < 4; ++ww)
                    val += ((float*)(Vt + ww * 4608))[(quad * 4 + r) * 68 + t * 16 + col16];
                const size_t row = (size_t)b * SEQ + i0 + quad * 4 + r;
                AO[row * DIM + h * HD + t * 16 + col16] =
                    __float2bfloat16(val / dn[r]);
            }
        }
    }
}

// ---------------------------------------------------------------------------
// LayerNorm over last dim (1024), sums the two split-K partials of O-proj.
// ---------------------------------------------------------------------------
__global__ __launch_bounds__(256) void ln_kernel(
    const float* __restrict__ Yp0,
    const float* __restrict__ Yp1,
    const float* __restrict__ gamma,
    const float* __restrict__ beta,
    float* __restrict__ out)
{
    const int row = blockIdx.x;
    const float* y0 = Yp0 + (size_t)row * DIM;
    const float* y1 = Yp1 + (size_t)row * DIM;

    float v[4];
    float s = 0.f, s2 = 0.f;
#pragma unroll
    for (int e = 0; e < 4; ++e) {
        const int idx = threadIdx.x + e * 256;
        v[e] = y0[idx] + y1[idx];
        s += v[e];
        s2 += v[e] * v[e];
    }
#pragma unroll
    for (int off = 1; off < 64; off <<= 1) {
        s  += __shfl_xor(s, off);
        s2 += __shfl_xor(s2, off);
    }
    __shared__ float ps[4], ps2[4];
    const int wave = threadIdx.x >> 6;
    if ((threadIdx.x & 63) == 0) { ps[wave] = s; ps2[wave] = s2; }
    __syncthreads();
    s  = ps[0] + ps[1] + ps[2] + ps[3];
    s2 = ps2[0] + ps2[1] + ps2[2] + ps2[3];

    const float mu   = s * (1.0f / DIM);
    const float var  = s2 * (1.0f / DIM) - mu * mu;
    const float rstd = rsqrtf(var + 1e-5f);

#pragma unroll
    for (int e = 0; e < 4; ++e) {
        const int idx = threadIdx.x + e * 256;
        out[(size_t)row * DIM + idx] =
            (v[e] - mu) * rstd * gamma[idx] + beta[idx];
    }
}

// ---------------------------------------------------------------------------
extern "C" void kernel_launch(void* const* d_in, const int* in_sizes, int n_in,
                              void* d_out, int out_size, void* d_ws, size_t ws_size,
                              hipStream_t stream)
{
    const float* x     = (const float*)d_in[0];
    const float* Wq    = (const float*)d_in[1];
    const float* bq    = (const float*)d_in[2];
    const float* Wk    = (const float*)d_in[3];
    const float* bk    = (const float*)d_in[4];
    const float* Wv    = (const float*)d_in[5];
    const float* bv    = (const float*)d_in[6];
    const float* Wo    = (const float*)d_in[7];
    const float* bo    = (const float*)d_in[8];
    const float* alpha = (const float*)d_in[9];
    const float* phi   = (const float*)d_in[10];
    const float* temp  = (const float*)d_in[11];
    const float* gamma = (const float*)d_in[12];
    const float* beta  = (const float*)d_in[13];

    float* out = (float*)d_out;

    const int B = 2;
    const int M = B * SEQ;                 // 2048

    // ws layout (MB):
    //   [0,4)   xb    [4,6) Wqb   [6,8) Wkb   [8,10) Wvb   [10,12) Wob
    //   [12,16) Qb    [16,20) Kb  [20,24) Vb  [24,28) AO
    //   Yp0 (fp32 8MB) aliases [0,8)  — xb/Wqb/Wkb dead by O-proj
    //   Yp1 (fp32 8MB) aliases [12,20) — Qb/Kb dead by O-proj
    char* wsb = (char*)d_ws;
    __hip_bfloat16* xb  = (__hip_bfloat16*)(wsb + 0);
    __hip_bfloat16* Wqb = (__hip_bfloat16*)(wsb + (4u  << 20));
    __hip_bfloat16* Wkb = (__hip_bfloat16*)(wsb + (6u  << 20));
    __hip_bfloat16* Wvb = (__hip_bfloat16*)(wsb + (8u  << 20));
    __hip_bfloat16* Wob = (__hip_bfloat16*)(wsb + (10u << 20));
    __hip_bfloat16* Qb  = (__hip_bfloat16*)(wsb + (12u << 20));
    __hip_bfloat16* Kb  = (__hip_bfloat16*)(wsb + (16u << 20));
    __hip_bfloat16* Vb  = (__hip_bfloat16*)(wsb + (20u << 20));
    __hip_bfloat16* AO  = (__hip_bfloat16*)(wsb + (24u << 20));
    float*          Yp0 = (float*)(wsb + 0);
    float*          Yp1 = (float*)(wsb + (12u << 20));

    hipLaunchKernelGGL(cvt_all, dim3(2048, 5), dim3(256), 0, stream,
                       x, Wq, Wk, Wv, Wo, xb, Wqb, Wkb, Wvb, Wob);

    hipLaunchKernelGGL(gemm_qkv, dim3(M / 64, DIM / 128, 3), dim3(256), 0, stream,
                       xb, Wqb, Wkb, Wvb, bq, bk, bv, Qb, Kb, Vb, M, DIM, DIM);

    hipLaunchKernelGGL(attn_kernel, dim3(SEQ / 16, B * NH), dim3(256), 0, stream,
                       Qb, Kb, Vb, alpha, phi, temp, AO);

    hipLaunchKernelGGL(gemm_osplit, dim3(M / 64, DIM / 128, 2), dim3(256), 0, stream,
                       AO, Wob, bo, Yp0, Yp1, M, DIM, DIM);

    hipLaunchKernelGGL(ln_kernel, dim3(M), dim3(256), 0, stream,
                       Yp0, Yp1, gamma, beta, out);
}

// Round 14
// 169.049 us; speedup vs baseline: 1.0666x; 1.0219x over previous
//
#include <hip/hip_runtime.h>
#include <hip/hip_bf16.h>

typedef short bf16x8 __attribute__((ext_vector_type(8)));
typedef float f32x4 __attribute__((ext_vector_type(4)));

#define MFMA16(a, b, c) __builtin_amdgcn_mfma_f32_16x16x32_bf16(a, b, c, 0, 0, 0)

static constexpr int SEQ = 1024;
static constexpr int DIM = 1024;
static constexpr int NH = 16;
static constexpr int HD = 64;

#if __has_builtin(__builtin_amdgcn_rcpf)
#define FAST_RCP(x) __builtin_amdgcn_rcpf(x)
#else
#define FAST_RCP(x) (1.0f / (x))
#endif

#if __has_builtin(__builtin_amdgcn_exp2f)
#define EXP2F(x) __builtin_amdgcn_exp2f(x)
#else
#define EXP2F(x) exp2f(x)
#endif

__device__ __forceinline__ int swz(int r) { return r ^ (r >> 3); } // row-XOR bank swizzle

// async global->LDS, 16B per lane. lds ptr must be wave-uniform (HW adds lane*16).
__device__ __forceinline__ void gload16(const __hip_bfloat16* g, __hip_bfloat16* l)
{
    typedef const __attribute__((address_space(1))) unsigned GU;
    typedef __attribute__((address_space(3))) unsigned LU;
    __builtin_amdgcn_global_load_lds((GU*)g, (LU*)l, 16, 0, 0);
}

__device__ __forceinline__ unsigned pack2bf(float a, float b)
{
    union { __hip_bfloat16 h; unsigned short u; } ca, cb;
    ca.h = __float2bfloat16(a); cb.h = __float2bfloat16(b);
    return (unsigned)ca.u | ((unsigned)cb.u << 16);
}

// ---------------------------------------------------------------------------
// fused fp32->bf16 conversion for all 5 tensors (grid.y selects region)
// ---------------------------------------------------------------------------
__global__ __launch_bounds__(256) void cvt_all(
    const float* __restrict__ x,  const float* __restrict__ wq,
    const float* __restrict__ wk, const float* __restrict__ wv,
    const float* __restrict__ wo,
    __hip_bfloat16* __restrict__ xb,  __hip_bfloat16* __restrict__ wqb,
    __hip_bfloat16* __restrict__ wkb, __hip_bfloat16* __restrict__ wvb,
    __hip_bfloat16* __restrict__ wob)
{
    const int reg = blockIdx.y;
    const float* src; __hip_bfloat16* dst; int n;
    if      (reg == 0) { src = x;  dst = xb;  n = 2 * SEQ * DIM; }
    else if (reg == 1) { src = wq; dst = wqb; n = DIM * DIM; }
    else if (reg == 2) { src = wk; dst = wkb; n = DIM * DIM; }
    else if (reg == 3) { src = wv; dst = wvb; n = DIM * DIM; }
    else               { src = wo; dst = wob; n = DIM * DIM; }
    const int i = (blockIdx.x * 256 + threadIdx.x) * 4;
    if (i < n) {
        float4 v = *(const float4*)(src + i);
        __hip_bfloat16 t[4];
        t[0] = __float2bfloat16(v.x); t[1] = __float2bfloat16(v.y);
        t[2] = __float2bfloat16(v.z); t[3] = __float2bfloat16(v.w);
        *(ushort4*)(dst + i) = *(ushort4*)t;
    }
}

// ---------------------------------------------------------------------------
// GEMM 64x128 tile, BK=64, gload_lds + XOR swizzle + single-barrier dbuf
// (exact R8 version, best-measured).
// ---------------------------------------------------------------------------
__global__ __launch_bounds__(256) void gemm_qkv(
    const __hip_bfloat16* __restrict__ A,
    const __hip_bfloat16* __restrict__ W0, const __hip_bfloat16* __restrict__ W1,
    const __hip_bfloat16* __restrict__ W2,
    const float* __restrict__ b0, const float* __restrict__ b1,
    const float* __restrict__ b2,
    __hip_bfloat16* __restrict__ Y0, __hip_bfloat16* __restrict__ Y1,
    __hip_bfloat16* __restrict__ Y2,
    int M, int N, int K)
{
    __shared__ __align__(16) __hip_bfloat16 As[2][64 * 64];
    __shared__ __align__(16) __hip_bfloat16 Ws[2][128 * 64];

    const int z = blockIdx.z;
    const __hip_bfloat16* W = (z == 0) ? W0 : ((z == 1) ? W1 : W2);
    const float* bias = (z == 0) ? b0 : ((z == 1) ? b1 : b2);
    __hip_bfloat16* Y = (z == 0) ? Y0 : ((z == 1) ? Y1 : Y2);

    const int tid = threadIdx.x;
    const int wv = tid >> 6, lane = tid & 63;
    const int col16 = lane & 15, quad = lane >> 4;
    const int m0 = blockIdx.x * 64, n0 = blockIdx.y * 128;
    const int wr = wv >> 1, wc = wv & 1;

    const int scol = ((tid & 7) ^ ((tid >> 3) & 7)) * 8;
    const __hip_bfloat16* ga = A + (size_t)(m0 + (tid >> 3)) * K + scol;
    const __hip_bfloat16* gb = W + (size_t)(n0 + (tid >> 3)) * K + scol;
    const int wofs = wv * 512;

    const int c7 = col16 & 7;
    const int so0 = ((quad)     ^ c7) * 8;
    const int so1 = ((quad + 4) ^ c7) * 8;

#define QKV_STAGE(k0, buf)                                         \
    {                                                              \
        __hip_bfloat16* lA = As[buf] + wofs;                       \
        __hip_bfloat16* lB = Ws[buf] + wofs;                       \
        gload16(ga + (k0),                    lA);                 \
        gload16(ga + (k0) + (size_t)32 * K,   lA + 2048);          \
        gload16(gb + (k0),                    lB);                 \
        gload16(gb + (k0) + (size_t)32 * K,   lB + 2048);          \
        gload16(gb + (k0) + (size_t)64 * K,   lB + 4096);          \
        gload16(gb + (k0) + (size_t)96 * K,   lB + 6144);          \
    }

    QKV_STAGE(0, 0);
    __syncthreads();

    f32x4 acc[8] = {};
    const int NT = K / 64;
    for (int t = 0; t < NT; ++t) {
        const int buf = t & 1;
        if (t + 1 < NT) QKV_STAGE((t + 1) * 64, buf ^ 1);
        const __hip_bfloat16* ar = As[buf] + (wr * 32 + col16) * 64;
        const __hip_bfloat16* br = Ws[buf] + (wc * 64 + col16) * 64;
#pragma unroll
        for (int kh = 0; kh < 2; ++kh) {
            const int so = (kh == 0) ? so0 : so1;
            bf16x8 af[2], bfm[4];
#pragma unroll
            for (int mt = 0; mt < 2; ++mt) af[mt]  = *(const bf16x8*)(ar + mt * 16 * 64 + so);
#pragma unroll
            for (int nt = 0; nt < 4; ++nt) bfm[nt] = *(const bf16x8*)(br + nt * 16 * 64 + so);
#pragma unroll
            for (int mt = 0; mt < 2; ++mt)
#pragma unroll
                for (int nt = 0; nt < 4; ++nt)
                    acc[mt * 4 + nt] = MFMA16(af[mt], bfm[nt], acc[mt * 4 + nt]);
        }
        __syncthreads();
    }
#undef QKV_STAGE

#pragma unroll
    for (int nt = 0; nt < 4; ++nt) {
        const int n = n0 + wc * 64 + nt * 16 + col16;
        const float bv = bias[n];
#pragma unroll
        for (int mt = 0; mt < 2; ++mt) {
#pragma unroll
            for (int r = 0; r < 4; ++r) {
                const int m = m0 + wr * 32 + mt * 16 + quad * 4 + r;
                Y[(size_t)m * N + n] = __float2bfloat16(acc[mt * 4 + nt][r] + bv);
            }
        }
    }
}

// ---------------------------------------------------------------------------
// O-proj split-K=2, same single-barrier dbuf structure (exact R8 version).
// ---------------------------------------------------------------------------
__global__ __launch_bounds__(256) void gemm_osplit(
    const __hip_bfloat16* __restrict__ A,
    const __hip_bfloat16* __restrict__ W,
    const float* __restrict__ bias,
    float* __restrict__ Y0, float* __restrict__ Y1,
    int M, int N, int K)
{
    __shared__ __align__(16) __hip_bfloat16 As[2][64 * 64];
    __shared__ __align__(16) __hip_bfloat16 Ws[2][128 * 64];

    const int z = blockIdx.z;
    float* Y = (z == 0) ? Y0 : Y1;
    const int kb = z * 512;

    const int tid = threadIdx.x;
    const int wv = tid >> 6, lane = tid & 63;
    const int col16 = lane & 15, quad = lane >> 4;
    const int m0 = blockIdx.x * 64, n0 = blockIdx.y * 128;
    const int wr = wv >> 1, wc = wv & 1;

    const int scol = ((tid & 7) ^ ((tid >> 3) & 7)) * 8;
    const __hip_bfloat16* ga = A + (size_t)(m0 + (tid >> 3)) * K + scol + kb;
    const __hip_bfloat16* gb = W + (size_t)(n0 + (tid >> 3)) * K + scol + kb;
    const int wofs = wv * 512;

    const int c7 = col16 & 7;
    const int so0 = ((quad)     ^ c7) * 8;
    const int so1 = ((quad + 4) ^ c7) * 8;

#define OS_STAGE(k0, buf)                                          \
    {                                                              \
        __hip_bfloat16* lA = As[buf] + wofs;                       \
        __hip_bfloat16* lB = Ws[buf] + wofs;                       \
        gload16(ga + (k0),                    lA);                 \
        gload16(ga + (k0) + (size_t)32 * K,   lA + 2048);          \
        gload16(gb + (k0),                    lB);                 \
        gload16(gb + (k0) + (size_t)32 * K,   lB + 2048);          \
        gload16(gb + (k0) + (size_t)64 * K,   lB + 4096);          \
        gload16(gb + (k0) + (size_t)96 * K,   lB + 6144);          \
    }

    OS_STAGE(0, 0);
    __syncthreads();

    f32x4 acc[8] = {};
    for (int t = 0; t < 8; ++t) {
        const int buf = t & 1;
        if (t + 1 < 8) OS_STAGE((t + 1) * 64, buf ^ 1);
        const __hip_bfloat16* ar = As[buf] + (wr * 32 + col16) * 64;
        const __hip_bfloat16* br = Ws[buf] + (wc * 64 + col16) * 64;
#pragma unroll
        for (int kh = 0; kh < 2; ++kh) {
            const int so = (kh == 0) ? so0 : so1;
            bf16x8 af[2], bfm[4];
#pragma unroll
            for (int mt = 0; mt < 2; ++mt) af[mt]  = *(const bf16x8*)(ar + mt * 16 * 64 + so);
#pragma unroll
            for (int nt = 0; nt < 4; ++nt) bfm[nt] = *(const bf16x8*)(br + nt * 16 * 64 + so);
#pragma unroll
            for (int mt = 0; mt < 2; ++mt)
#pragma unroll
                for (int nt = 0; nt < 4; ++nt)
                    acc[mt * 4 + nt] = MFMA16(af[mt], bfm[nt], acc[mt * 4 + nt]);
        }
        __syncthreads();
    }
#undef OS_STAGE

#pragma unroll
    for (int nt = 0; nt < 4; ++nt) {
        const int n = n0 + wc * 64 + nt * 16 + col16;
        const float bv = (z == 0) ? bias[n] : 0.0f;
#pragma unroll
        for (int mt = 0; mt < 2; ++mt) {
#pragma unroll
            for (int r = 0; r < 4; ++r) {
                const int m = m0 + wr * 32 + mt * 16 + quad * 4 + r;
                Y[(size_t)m * N + n] = acc[mt * 4 + nt][r] + bv;
            }
        }
    }
}

// ---------------------------------------------------------------------------
// Attention — exact R8 version (best-measured: swapped QK^T + in-register P,
// Vt double-buffer ping-pong, 1 barrier/iter). R12/R13's barrier-free variant
// reverted: correct but +6us from staging bank conflicts (2.1M -> 7.3M).
// ---------------------------------------------------------------------------
__global__ __launch_bounds__(256) void attn_kernel(
    const __hip_bfloat16* __restrict__ Q,
    const __hip_bfloat16* __restrict__ K,
    const __hip_bfloat16* __restrict__ V,
    const float* __restrict__ alpha, const float* __restrict__ phi,
    const float* __restrict__ temperature,
    __hip_bfloat16* __restrict__ AO)
{
    __shared__ __align__(16) char smem[2 * 18432 + 512];
    __hip_bfloat16* VtBase = (__hip_bfloat16*)smem;          // [2][2half][64*72]
    float* Ocomb = (float*)smem;                 // [2][16][68] (epilogue reuse)
    float* Dl    = (float*)(smem + 2 * 18432);   // [2][32]

    const int tid = threadIdx.x;
    const int wv = tid >> 6, lane = tid & 63;
    const int col16 = lane & 15, quad = lane >> 4;
    const int g = wv & 1, half = wv >> 1;

    const int bh = blockIdx.y, b = bh >> 4, h = bh & 15;
    const int i0 = blockIdx.x * 32 + g * 16;
    const size_t base = ((size_t)b * SEQ) * DIM + (size_t)h * HD;

    const float tempv = fabsf(temperature[0]) + 0.1f;
    const float simscale = 1.0f / (8.0f * tempv);
    const float freqs[5] = {31.0f, 37.0f, 41.0f, 43.0f, 47.0f};

    // degree-7 poly of log2e*score(s); w = rcp(1+exp2(-poly(s)))  [R5-validated]
    float p[8] = {0.f, 0.f, 0.f, 0.f, 0.f, 0.f, 0.f, 0.f};
#pragma unroll
    for (int f = 0; f < 5; ++f) {
        const float a  = alpha[h * 5 + f] * 1.44269504089f;  // fold log2(e)
        const float ph = phi[h * 5 + f];
        const float sp = __sinf(ph), cp = __cosf(ph);
        const float c  = 6.28318530718f * simscale / freqs[f];
        const float c2 = c * c, c3 = c2 * c, c4 = c2 * c2;
        const float c5 = c4 * c, c6 = c4 * c2, c7 = c4 * c3;
        p[0] += a * sp;
        p[1] += a * cp * c;
        p[2] -= a * sp * c2 * 0.5f;
        p[3] -= a * cp * c3 * (1.0f / 6.0f);
        p[4] += a * sp * c4 * (1.0f / 24.0f);
        p[5] += a * cp * c5 * (1.0f / 120.0f);
        p[6] -= a * sp * c6 * (1.0f / 720.0f);
        p[7] -= a * cp * c7 * (1.0f / 5040.0f);
    }

    const __hip_bfloat16* qrow = Q + base + (size_t)(i0 + col16) * DIM + quad * 8;
    const bf16x8 qa0 = *(const bf16x8*)(qrow);
    const bf16x8 qa1 = *(const bf16x8*)(qrow + 32);

    const __hip_bfloat16* kbase = K + base + (size_t)col16 * DIM + quad * 8;

    const int tl = tid & 127;
    const int sc0 = (tl & 7) * 8;
    const int sx  = tl & 7;
    const int jj0 = (tl >> 3) * 2;
    // column permutation pi(j) within 32-j sub-block (j-pair keeps r,r+1 adjacent)
    const int pu = (jj0 >> 4) & 1, pqs = (jj0 >> 2) & 3, pr = jj0 & 3;
    const int col0 = ((pqs ^ (pu << 1)) << 3) + (pu << 2) + pr;   // pi(jj0)
    __hip_bfloat16* VtH = VtBase + half * 4608;    // buf stride = 9216 elements
    __hip_bfloat16* rowp[8];
#pragma unroll
    for (int e = 0; e < 8; ++e) rowp[e] = VtH + (sc0 + (e ^ sx)) * 72;

    const __hip_bfloat16* vrd[4];
#pragma unroll
    for (int t = 0; t < 4; ++t)
        vrd[t] = VtH + swz(t * 16 + col16) * 72 + quad * 8;

    f32x4 o[4] = {};
    float denomL = 0.f;

    bf16x8 vr[2][2];   // prefetched V regs (V(j) for next pack)
    bf16x8 kf[4][2];   // prefetched K frags

#define LOADV(jt)                                                              \
    {                                                                          \
        const int jv = half * 512 + (jt) * 64;                                 \
        _Pragma("unroll")                                                      \
        for (int s = 0; s < 2; ++s) {                                          \
            const __hip_bfloat16* vp =                                         \
                V + base + (size_t)(jv + jj0 + 32 * s) * DIM + sc0;            \
            vr[s][0] = *(const bf16x8*)(vp);                                   \
            vr[s][1] = *(const bf16x8*)(vp + DIM);                             \
        }                                                                      \
    }

#define PACKV(pofs)                                                            \
    {                                                                          \
        _Pragma("unroll")                                                      \
        for (int s = 0; s < 2; ++s) {                                          \
            _Pragma("unroll")                                                  \
            for (int e = 0; e < 8; ++e) {                                      \
                unsigned pk = ((unsigned)(unsigned short)vr[s][0][e]) |        \
                              (((unsigned)(unsigned short)vr[s][1][e]) << 16); \
                *(unsigned*)(rowp[e] + (pofs) + col0 + 32 * s) = pk;           \
            }                                                                  \
        }                                                                      \
    }

    // prologue: V(0) -> buf0; preload V(1), K(0)
    LOADV(0);
    PACKV(0);
    LOADV(1);
    {
        const int j0 = half * 512;
#pragma unroll
        for (int u = 0; u < 4; ++u) {
            const __hip_bfloat16* kp = kbase + (size_t)(j0 + u * 16) * DIM;
            kf[u][0] = *(const bf16x8*)(kp);
            kf[u][1] = *(const bf16x8*)(kp + 32);
        }
    }
    __syncthreads();   // buf0 visible

    for (int it = 0; it < 8; ++it) {
        const int cur = it & 1;
        if (it < 7) PACKV((cur ^ 1) * 9216);
        if (it < 6) LOADV(it + 2);

        // swapped QK^T: lane holds S[j = u*16 + quad*4 + r][i = col16]
        f32x4 sa4[4];
        __builtin_amdgcn_s_setprio(1);
#pragma unroll
        for (int u = 0; u < 4; ++u) {
            f32x4 zz = {};
            zz = MFMA16(kf[u][0], qa0, zz);
            zz = MFMA16(kf[u][1], qa1, zz);
            sa4[u] = zz;
        }
        __builtin_amdgcn_s_setprio(0);

        if (it < 7) {
            const int j1 = half * 512 + (it + 1) * 64;
#pragma unroll
            for (int u = 0; u < 4; ++u) {
                const __hip_bfloat16* kp = kbase + (size_t)(j1 + u * 16) * DIM;
                kf[u][0] = *(const bf16x8*)(kp);
                kf[u][1] = *(const bf16x8*)(kp + 32);
            }
        }

#pragma unroll
        for (int sub = 0; sub < 2; ++sub) {
            float w[2][4];
#pragma unroll
            for (int s2 = 0; s2 < 2; ++s2) {
                const int u = sub * 2 + s2;
#pragma unroll
                for (int r = 0; r < 4; ++r) {
                    const float sv = sa4[u][r];
                    float sc = fmaf(sv, p[7], p[6]);
                    sc = fmaf(sv, sc, p[5]);
                    sc = fmaf(sv, sc, p[4]);
                    sc = fmaf(sv, sc, p[3]);
                    sc = fmaf(sv, sc, p[2]);
                    sc = fmaf(sv, sc, p[1]);
                    sc = fmaf(sv, sc, p[0]);
                    const float ww = FAST_RCP(1.0f + EXP2F(-sc));
                    denomL += ww;
                    w[s2][r] = ww;
                }
            }
            // in-register P fragment: u'=0 stays, u'=1 crosses lane^32
            const unsigned pk00 = pack2bf(w[0][0], w[0][1]);
            const unsigned pk01 = pack2bf(w[0][2], w[0][3]);
            const unsigned pk10 = pack2bf(w[1][0], w[1][1]);
            const unsigned pk11 = pack2bf(w[1][2], w[1][3]);
            const unsigned sw0 = (unsigned)__shfl_xor((int)pk10, 32);
            const unsigned sw1 = (unsigned)__shfl_xor((int)pk11, 32);
            union { unsigned d[4]; bf16x8 v; } pu8;
            pu8.d[0] = pk00; pu8.d[1] = pk01; pu8.d[2] = sw0; pu8.d[3] = sw1;
            const bf16x8 pa = pu8.v;

            __builtin_amdgcn_s_setprio(1);
#pragma unroll
            for (int t = 0; t < 4; ++t) {
                bf16x8 vb = *(const bf16x8*)(vrd[t] + cur * 9216 + 32 * sub);
                o[t] = MFMA16(pa, vb, o[t]);
            }
            __builtin_amdgcn_s_setprio(0);
        }
        __syncthreads();   // Vt[cur^1] packed & visible; Vt[cur] reads done
    }
#undef LOADV
#undef PACKV

    // denom: lane holds partial for i=col16 over its js; reduce across quads
    denomL += __shfl_xor(denomL, 16);
    denomL += __shfl_xor(denomL, 32);

    if (quad == 0) Dl[half * 32 + g * 16 + col16] = denomL;
    if (half == 1) {
#pragma unroll
        for (int t = 0; t < 4; ++t)
#pragma unroll
            for (int r = 0; r < 4; ++r)
                Ocomb[(g * 16 + quad * 4 + r) * 68 + t * 16 + col16] = o[t][r];
    }
    __syncthreads();
    if (half == 0) {
        float dn[4];
#pragma unroll
        for (int r = 0; r < 4; ++r)
            dn[r] = Dl[g * 16 + quad * 4 + r] + Dl[32 + g * 16 + quad * 4 + r] + 1e-10f;
#pragma unroll
        for (int t = 0; t < 4; ++t) {
#pragma unroll
            for (int r = 0; r < 4; ++r) {
                const float val =
                    (o[t][r] + Ocomb[(g * 16 + quad * 4 + r) * 68 + t * 16 + col16]) / dn[r];
                const size_t row = (size_t)b * SEQ + i0 + quad * 4 + r;
                AO[row * DIM + h * HD + t * 16 + col16] = __float2bfloat16(val);
            }
        }
    }
}

// ---------------------------------------------------------------------------
// LayerNorm over last dim (1024), sums the two split-K partials of O-proj.
// ---------------------------------------------------------------------------
__global__ __launch_bounds__(256) void ln_kernel(
    const float* __restrict__ Yp0,
    const float* __restrict__ Yp1,
    const float* __restrict__ gamma,
    const float* __restrict__ beta,
    float* __restrict__ out)
{
    const int row = blockIdx.x;
    const float* y0 = Yp0 + (size_t)row * DIM;
    const float* y1 = Yp1 + (size_t)row * DIM;

    float v[4];
    float s = 0.f, s2 = 0.f;
#pragma unroll
    for (int e = 0; e < 4; ++e) {
        const int idx = threadIdx.x + e * 256;
        v[e] = y0[idx] + y1[idx];
        s += v[e];
        s2 += v[e] * v[e];
    }
#pragma unroll
    for (int off = 1; off < 64; off <<= 1) {
        s  += __shfl_xor(s, off);
        s2 += __shfl_xor(s2, off);
    }
    __shared__ float ps[4], ps2[4];
    const int wave = threadIdx.x >> 6;
    if ((threadIdx.x & 63) == 0) { ps[wave] = s; ps2[wave] = s2; }
    __syncthreads();
    s  = ps[0] + ps[1] + ps[2] + ps[3];
    s2 = ps2[0] + ps2[1] + ps2[2] + ps2[3];

    const float mu   = s * (1.0f / DIM);
    const float var  = s2 * (1.0f / DIM) - mu * mu;
    const float rstd = rsqrtf(var + 1e-5f);

#pragma unroll
    for (int e = 0; e < 4; ++e) {
        const int idx = threadIdx.x + e * 256;
        out[(size_t)row * DIM + idx] =
            (v[e] - mu) * rstd * gamma[idx] + beta[idx];
    }
}

// ---------------------------------------------------------------------------
extern "C" void kernel_launch(void* const* d_in, const int* in_sizes, int n_in,
                              void* d_out, int out_size, void* d_ws, size_t ws_size,
                              hipStream_t stream)
{
    const float* x     = (const float*)d_in[0];
    const float* Wq    = (const float*)d_in[1];
    const float* bq    = (const float*)d_in[2];
    const float* Wk    = (const float*)d_in[3];
    const float* bk    = (const float*)d_in[4];
    const float* Wv    = (const float*)d_in[5];
    const float* bv    = (const float*)d_in[6];
    const float* Wo    = (const float*)d_in[7];
    const float* bo    = (const float*)d_in[8];
    const float* alpha = (const float*)d_in[9];
    const float* phi   = (const float*)d_in[10];
    const float* temp  = (const float*)d_in[11];
    const float* gamma = (const float*)d_in[12];
    const float* beta  = (const float*)d_in[13];

    float* out = (float*)d_out;

    const int B = 2;
    const int M = B * SEQ;                 // 2048

    // ws layout (MB):
    //   [0,4)   xb    [4,6) Wqb   [6,8) Wkb   [8,10) Wvb   [10,12) Wob
    //   [12,16) Qb    [16,20) Kb  [20,24) Vb  [24,28) AO
    //   Yp0 (fp32 8MB) aliases [0,8)  — xb/Wqb/Wkb dead by O-proj
    //   Yp1 (fp32 8MB) aliases [12,20) — Qb/Kb dead by O-proj
    char* wsb = (char*)d_ws;
    __hip_bfloat16* xb  = (__hip_bfloat16*)(wsb + 0);
    __hip_bfloat16* Wqb = (__hip_bfloat16*)(wsb + (4u  << 20));
    __hip_bfloat16* Wkb = (__hip_bfloat16*)(wsb + (6u  << 20));
    __hip_bfloat16* Wvb = (__hip_bfloat16*)(wsb + (8u  << 20));
    __hip_bfloat16* Wob = (__hip_bfloat16*)(wsb + (10u << 20));
    __hip_bfloat16* Qb  = (__hip_bfloat16*)(wsb + (12u << 20));
    __hip_bfloat16* Kb  = (__hip_bfloat16*)(wsb + (16u << 20));
    __hip_bfloat16* Vb  = (__hip_bfloat16*)(wsb + (20u << 20));
    __hip_bfloat16* AO  = (__hip_bfloat16*)(wsb + (24u << 20));
    float*          Yp0 = (float*)(wsb + 0);
    float*          Yp1 = (float*)(wsb + (12u << 20));

    hipLaunchKernelGGL(cvt_all, dim3(2048, 5), dim3(256), 0, stream,
                       x, Wq, Wk, Wv, Wo, xb, Wqb, Wkb, Wvb, Wob);

    hipLaunchKernelGGL(gemm_qkv, dim3(M / 64, DIM / 128, 3), dim3(256), 0, stream,
                       xb, Wqb, Wkb, Wvb, bq, bk, bv, Qb, Kb, Vb, M, DIM, DIM);

    hipLaunchKernelGGL(attn_kernel, dim3(SEQ / 32, B * NH), dim3(256), 0, stream,
                       Qb, Kb, Vb, alpha, phi, temp, AO);

    hipLaunchKernelGGL(gemm_osplit, dim3(M / 64, DIM / 128, 2), dim3(256), 0, stream,
                       AO, Wob, bo, Yp0, Yp1, M, DIM, DIM);

    hipLaunchKernelGGL(ln_kernel, dim3(M), dim3(256), 0, stream,
                       Yp0, Yp1, gamma, beta, out);
}